// Round 18
// baseline (297.216 us; speedup 1.0000x reference)
//
#include <hip/hip_runtime.h>
#include <hip/hip_bf16.h>

// Problem constants (B=4, S=2048, D=1024, E=8, F=4096)
#define TOKENS   8192
#define DDIM     1024
#define NEXP     8
#define FDIM     4096
#define CAPACITY 1280
#define NYT      10         // CAPACITY / 128 M-tiles
#define NWG1     ((FDIM / 128) * NYT * NEXP)          // 2560 gemm1 blocks
#define NWGT2    ((DDIM / 64) * (FDIM / 64) * NEXP)   // 8192 W2-transpose blocks
#define NWGD     (NEXP * CAPACITY)                    // 10240 dispatch blocks
#define NWGT1    ((FDIM / 64) * (DDIM / 64) * NEXP)   // 8192 W1-transpose blocks

typedef __attribute__((ext_vector_type(8))) __bf16 bf16x8;
typedef __attribute__((ext_vector_type(4))) __bf16 bf16x4;
typedef __attribute__((ext_vector_type(4))) float  f32x4;

typedef __attribute__((address_space(1))) const void gvoid_t;
typedef __attribute__((address_space(3))) void       lvoid_t;

__device__ __forceinline__ void async16(const void* g, void* l) {
  // 16B per lane; LDS dest = wave-uniform base + lane*16 (HW behavior)
  __builtin_amdgcn_global_load_lds((gvoid_t*)g, (lvoid_t*)l, 16, 0, 0);
}

// ---------------- gating: logits, softmax, top-1 (all f32, must match ref routing) --------
__global__ void gate_kernel(const float* __restrict__ x, const float* __restrict__ gw,
                            int* __restrict__ eidx, float* __restrict__ prob) {
  const int t = blockIdx.x;
  const int lane = threadIdx.x;           // 64 threads
  const float* xp = x + (size_t)t * DDIM;
  float acc[NEXP];
#pragma unroll
  for (int e = 0; e < NEXP; ++e) acc[e] = 0.f;
#pragma unroll 4
  for (int i = 0; i < DDIM / 64; ++i) {
    const int d = i * 64 + lane;
    const float xv = xp[d];
    const f32x4 g0 = *(const f32x4*)(gw + d * NEXP);
    const f32x4 g1 = *(const f32x4*)(gw + d * NEXP + 4);
    acc[0] += xv * g0[0]; acc[1] += xv * g0[1];
    acc[2] += xv * g0[2]; acc[3] += xv * g0[3];
    acc[4] += xv * g1[0]; acc[5] += xv * g1[1];
    acc[6] += xv * g1[2]; acc[7] += xv * g1[3];
  }
#pragma unroll
  for (int e = 0; e < NEXP; ++e) {
    float v = acc[e];
#pragma unroll
    for (int off = 32; off; off >>= 1) v += __shfl_xor(v, off);
    acc[e] = v;
  }
  if (lane == 0) {
    float m = acc[0]; int mi = 0;
#pragma unroll
    for (int e = 1; e < NEXP; ++e) if (acc[e] > m) { m = acc[e]; mi = e; }  // first-occurrence argmax
    float s = 0.f;
#pragma unroll
    for (int e = 0; e < NEXP; ++e) s += __expf(acc[e] - m);
    eidx[t] = mi;
    prob[t] = 1.f / s;       // softmax prob of the argmax expert
  }
}

// ---------------- deterministic per-expert cumsum positions + slot->token map + counts ----
__global__ void scan_kernel(const int* __restrict__ eidx, int* __restrict__ src,
                            int* __restrict__ counts) {
  __shared__ int buf[2][NEXP][256];
  const int tid = threadIdx.x;            // 256 threads, 1 block
  for (int i = tid; i < NEXP * CAPACITY; i += 256) src[i] = -1;
  const int t0 = tid * (TOKENS / 256);    // 32 tokens per thread
#pragma unroll
  for (int e = 0; e < NEXP; ++e) buf[0][e][tid] = 0;
  for (int k = 0; k < TOKENS / 256; ++k) {
    const int e = eidx[t0 + k];
    buf[0][e][tid]++;                     // LDS histogram
  }
  __syncthreads();
  int cur = 0;
  for (int off = 1; off < 256; off <<= 1) {   // Hillis-Steele inclusive scan over threads
#pragma unroll
    for (int e = 0; e < NEXP; ++e) {
      int v = buf[cur][e][tid];
      if (tid >= off) v += buf[cur][e][tid - off];
      buf[cur ^ 1][e][tid] = v;
    }
    __syncthreads();
    cur ^= 1;
  }
  if (tid < NEXP) counts[tid] = buf[cur][tid][255];   // per-expert totals (for M-tile skip)
  // exclusive base -> running counters in the other buffer (own slot only, no race)
#pragma unroll
  for (int e = 0; e < NEXP; ++e)
    buf[cur ^ 1][e][tid] = (tid > 0) ? buf[cur][e][tid - 1] : 0;
  for (int k = 0; k < TOKENS / 256; ++k) {
    const int t = t0 + k;
    const int e = eidx[t];
    const int p = buf[cur ^ 1][e][tid]++;
    if (p < CAPACITY) src[e * CAPACITY + p] = t;   // p>=CAP => token dropped
  }
}

// ---------------- FUSED: dispatch (blocks [0,NWGD)) + W1 transpose (blocks [NWGD,...)) ----
// Dispatch (54MB, no LDS) and the W1 transpose (201MB, 8.4KB LDS) are independent
// (W1bT feeds only gemm1; dispatch needs only scan's src). Same heterogeneous
// block-range fusion that won R17: combined ~255MB ≈ 40us at the BW wall, replacing
// ~45us serial + one launch gap.
__global__ void fused_dw1t_kernel(const float* __restrict__ tokens,
                                  const int* __restrict__ src,
                                  __bf16* __restrict__ Xb,
                                  const float* __restrict__ w1,
                                  __bf16* __restrict__ w1t) {
  __shared__ __bf16 tile[64][66];         // transpose tile; dispatch blocks don't touch it

  if (blockIdx.x < NWGD) {
    // ---------------- dispatch: f32 -> bf16 scatter into [E*CAP, D] ----------------
    const int slot = blockIdx.x;
    const int tid  = threadIdx.x;         // 256 threads, 4 elems each
    const int t = src[slot];
    bf16x4* dst = (bf16x4*)(Xb + (size_t)slot * DDIM);
    bf16x4 o;
    if (t >= 0) {
      const f32x4 v = ((const f32x4*)(tokens + (size_t)t * DDIM))[tid];
      o[0] = (__bf16)v[0]; o[1] = (__bf16)v[1]; o[2] = (__bf16)v[2]; o[3] = (__bf16)v[3];
    } else {
      o[0] = (__bf16)0.f; o[1] = (__bf16)0.f; o[2] = (__bf16)0.f; o[3] = (__bf16)0.f;
    }
    dst[tid] = o;
  } else {
    // ---------------- W1 transpose: w1[e][D][F] -> w1t[e][F][D] ----------------
    constexpr int R = DDIM, C = FDIM;     // R/64 = 16, C/64 = 64
    const int idx = blockIdx.x - NWGD;    // 0 .. 8191
    const int e   = idx >> 10;            // / 1024
    const int rem = idx & 1023;
    const int by  = rem >> 6;             // 0..15 over R/64
    const int bx  = rem & 63;             // 0..63 over C/64
    const float* wp = w1 + (size_t)e * R * C;
    __bf16* op = w1t + (size_t)e * R * C;
    const int c0 = bx * 64, r0 = by * 64;
    const int tid = threadIdx.x;          // 256 threads
#pragma unroll
    for (int p = 0; p < 4; ++p) {         // load 16 rows/pass, f32x4 per thread
      const int r = p * 16 + (tid >> 4);
      const int c = (tid & 15) * 4;
      const f32x4 v = *(const f32x4*)(wp + (size_t)(r0 + r) * C + c0 + c);
      tile[r][c]     = (__bf16)v[0]; tile[r][c + 1] = (__bf16)v[1];
      tile[r][c + 2] = (__bf16)v[2]; tile[r][c + 3] = (__bf16)v[3];
    }
    __syncthreads();
#pragma unroll
    for (int p = 0; p < 2; ++p) {         // store 32 out-rows/pass, bf16x8 per thread
      const int c  = p * 32 + (tid >> 3);
      const int rg = (tid & 7) * 8;
      bf16x8 o;
#pragma unroll
      for (int i = 0; i < 8; ++i) o[i] = tile[rg + i][c];
      *(bf16x8*)(op + (size_t)(c0 + c) * R + r0 + rg) = o;
    }
  }
}

// ---------------- FUSED: gemm1 (blocks [0,NWG1)) + W2 transpose (blocks [NWG1, ...)) ------
// R17 measured: 112us total — W2 transpose absorbed at ~zero cost under gemm1's idle
// HBM/wave capacity. gemm1 body = R8 measured-best form, byte-identical logic.
__global__ __launch_bounds__(256, 2)
void fused_g1w2t_kernel(const __bf16* __restrict__ A, const __bf16* __restrict__ B,
                        __bf16* __restrict__ Cbf, const int* __restrict__ counts,
                        const float* __restrict__ w2, __bf16* __restrict__ w2t) {
  __shared__ char smem[32768];            // gemm1: 2x16KB tiles; transpose: 8.4KB tile

  if (blockIdx.x < NWG1) {
    // ================= gemm1: 128x128, BK=64, 4 waves (R8 form) =================
    constexpr int N  = FDIM;
    constexpr int NX = N / 128;
    constexpr int K  = DDIM;
    __bf16* lds0 = (__bf16*)smem;           // A tile [128][64]
    __bf16* lds1 = (__bf16*)(smem + 16384); // B tile [128][64]

    const int nwg = NX * NYT * NEXP;        // 2560
    int wg = blockIdx.x;
    wg = (wg & 7) * (nwg >> 3) + (wg >> 3); // bijective XCD swizzle (nwg % 8 == 0)
    const int e   = wg / (NX * NYT);
    const int rem = wg - e * (NX * NYT);
    const int ty  = rem % NYT;              // y fastest: consecutive ids share B-panel (L2)
    const int tx  = rem / NYT;
    const int m0  = ty * 128, n0 = tx * 128;

    const int cnt   = counts[e];            // M-tile skip
    const int tiles = (cnt + 127) >> 7;
    if (ty >= ((tiles < NYT) ? tiles : NYT)) return;

    const __bf16* Ae = A + (size_t)e * ((size_t)CAPACITY * DDIM);
    const __bf16* Be = B + (size_t)e * ((size_t)FDIM * DDIM);
    const int tid = threadIdx.x;
    const int wid = tid >> 6, lane = tid & 63;
    const int wm = wid >> 1, wn = wid & 1;  // 2x2 wave grid, per-wave out 64x64
    const int rl = lane & 15, gl = lane >> 4;

    f32x4 acc[4][4];
#pragma unroll
    for (int m = 0; m < 4; ++m)
#pragma unroll
      for (int n = 0; n < 4; ++n) acc[m][n] = (f32x4){0.f, 0.f, 0.f, 0.f};

    for (int kt = 0; kt < K; kt += 64) {
#pragma unroll
      for (int i = 0; i < 4; ++i) {         // stage 16KB A + 16KB B, source pre-swizzled
        const int s   = (wid * 4 + i) * 64 + lane;
        const int row = s >> 3;
        const int cg  = (s & 7) ^ (row & 7);
        async16(Ae + (size_t)(m0 + row) * K + kt + cg * 8, &lds0[(wid * 4 + i) * 512]);
        async16(Be + (size_t)(n0 + row) * K + kt + cg * 8, &lds1[(wid * 4 + i) * 512]);
      }
      __syncthreads();
      const char* la = (const char*)lds0;
      const char* lb = (const char*)lds1;
#pragma unroll
      for (int kk = 0; kk < 2; ++kk) {
        bf16x8 af[4], bv[4];
#pragma unroll
        for (int m = 0; m < 4; ++m) {
          const int rowin = wm * 64 + m * 16 + rl;
          af[m] = *(const bf16x8*)(la + rowin * 128 + (((kk * 4 + gl) ^ (rowin & 7)) * 16));
        }
#pragma unroll
        for (int n = 0; n < 4; ++n) {
          const int rowin = wn * 64 + n * 16 + rl;
          bv[n] = *(const bf16x8*)(lb + rowin * 128 + (((kk * 4 + gl) ^ (rowin & 7)) * 16));
        }
#pragma unroll
        for (int m = 0; m < 4; ++m)
#pragma unroll
          for (int n = 0; n < 4; ++n)
            acc[m][n] = __builtin_amdgcn_mfma_f32_16x16x32_bf16(af[m], bv[n], acc[m][n], 0, 0, 0);
      }
      __syncthreads();
    }

    // C/D layout: col = lane&15, row = (lane>>4)*4 + reg  [m89/m91 verified]
    __bf16* Ce = Cbf + (size_t)e * ((size_t)CAPACITY * FDIM);
#pragma unroll
    for (int m = 0; m < 4; ++m)
#pragma unroll
      for (int j = 0; j < 4; ++j) {
        const int row = m0 + wm * 64 + m * 16 + gl * 4 + j;
#pragma unroll
        for (int n = 0; n < 4; ++n) {
          const int col = n0 + wn * 64 + n * 16 + rl;
          float v = acc[m][n][j];
          v = v > 0.f ? v : 0.f;            // fused ReLU
          Ce[(size_t)row * N + col] = (__bf16)v;
        }
      }
  } else {
    // ================= W2 transpose: w2[e][F][D] -> w2t[e][D][F] =================
    constexpr int R = FDIM, C = DDIM;
    const int idx = blockIdx.x - NWG1;      // 0 .. 8191
    const int e   = idx >> 10;              // / (16*64)
    const int rem = idx & 1023;
    const int by  = rem >> 4;               // 0..63 over R/64
    const int bx  = rem & 15;               // 0..15 over C/64
    auto tile = [&](int r, int c) -> __bf16& {
      return *(__bf16*)(smem + ((r * 66 + c) << 1));
    };
    const float* wp = w2 + (size_t)e * R * C;
    __bf16* op = w2t + (size_t)e * R * C;
    const int c0 = bx * 64, r0 = by * 64;
    const int tid = threadIdx.x;            // 256 threads
#pragma unroll
    for (int p = 0; p < 4; ++p) {           // load 16 rows/pass, f32x4 per thread
      const int r = p * 16 + (tid >> 4);
      const int c = (tid & 15) * 4;
      const f32x4 v = *(const f32x4*)(wp + (size_t)(r0 + r) * C + c0 + c);
      tile(r, c)     = (__bf16)v[0]; tile(r, c + 1) = (__bf16)v[1];
      tile(r, c + 2) = (__bf16)v[2]; tile(r, c + 3) = (__bf16)v[3];
    }
    __syncthreads();
#pragma unroll
    for (int p = 0; p < 2; ++p) {           // store 32 out-rows/pass, bf16x8 per thread
      const int c  = p * 32 + (tid >> 3);
      const int rg = (tid & 7) * 8;
      bf16x8 o;
#pragma unroll
      for (int i = 0; i < 8; ++i) o[i] = tile(rg + i, c);
      *(bf16x8*)(op + (size_t)(c0 + c) * R + r0 + rg) = o;
    }
  }
}

// ---------------- GEMM2: 128x128, BK=64, 4 waves, bf16 B^T via async16 (R6 form) ----------
// out[t] = prob[t] * (H[e] @ W2bT[e][N,K]^T)[slot].  Measured ~112-116us (R17).
__global__ __launch_bounds__(256, 2)
void gemm2_kernel(const __bf16* __restrict__ A, const __bf16* __restrict__ B,
                  float* __restrict__ out, const int* __restrict__ src,
                  const float* __restrict__ prob, const int* __restrict__ counts,
                  int K, size_t sA, size_t sB) {
  constexpr int N  = DDIM;
  constexpr int NX = N / 128;
  __shared__ __bf16 lds[2][128 * 64];     // [0]=A tile [128][64], [1]=B tile (32 KB total)

  const int nwg = NX * NYT * NEXP;
  int wg = blockIdx.x;
  wg = (wg & 7) * (nwg >> 3) + (wg >> 3); // bijective XCD swizzle (nwg % 8 == 0)
  const int e   = wg / (NX * NYT);
  const int rem = wg - e * (NX * NYT);
  const int ty  = rem % NYT;              // y fastest: consecutive ids share B-panel (L2)
  const int tx  = rem / NYT;
  const int m0  = ty * 128, n0 = tx * 128;

  const int cnt   = counts[e];            // M-tile skip
  const int tiles = (cnt + 127) >> 7;
  if (ty >= ((tiles < NYT) ? tiles : NYT)) return;

  const __bf16* Ae = A + (size_t)e * sA;
  const __bf16* Be = B + (size_t)e * sB;
  const int tid = threadIdx.x;
  const int wid = tid >> 6, lane = tid & 63;
  const int wm = wid >> 1, wn = wid & 1;  // 2x2 wave grid, per-wave out 64x64
  const int rl = lane & 15, gl = lane >> 4;

  f32x4 acc[4][4];
#pragma unroll
  for (int m = 0; m < 4; ++m)
#pragma unroll
    for (int n = 0; n < 4; ++n) acc[m][n] = (f32x4){0.f, 0.f, 0.f, 0.f};

  for (int kt = 0; kt < K; kt += 64) {
#pragma unroll
    for (int i = 0; i < 4; ++i) {         // stage 16KB A + 16KB B, source pre-swizzled
      const int s   = (wid * 4 + i) * 64 + lane;
      const int row = s >> 3;
      const int cg  = (s & 7) ^ (row & 7);
      async16(Ae + (size_t)(m0 + row) * K + kt + cg * 8, &lds[0][(wid * 4 + i) * 512]);
      async16(Be + (size_t)(n0 + row) * K + kt + cg * 8, &lds[1][(wid * 4 + i) * 512]);
    }
    __syncthreads();
    const char* la = (const char*)&lds[0][0];
    const char* lb = (const char*)&lds[1][0];
#pragma unroll
    for (int kk = 0; kk < 2; ++kk) {
      bf16x8 af[4], bv[4];
#pragma unroll
      for (int m = 0; m < 4; ++m) {
        const int rowin = wm * 64 + m * 16 + rl;
        af[m] = *(const bf16x8*)(la + rowin * 128 + (((kk * 4 + gl) ^ (rowin & 7)) * 16));
      }
#pragma unroll
      for (int n = 0; n < 4; ++n) {
        const int rowin = wn * 64 + n * 16 + rl;
        bv[n] = *(const bf16x8*)(lb + rowin * 128 + (((kk * 4 + gl) ^ (rowin & 7)) * 16));
      }
#pragma unroll
      for (int m = 0; m < 4; ++m)
#pragma unroll
        for (int n = 0; n < 4; ++n)
          acc[m][n] = __builtin_amdgcn_mfma_f32_16x16x32_bf16(af[m], bv[n], acc[m][n], 0, 0, 0);
    }
    __syncthreads();
  }

  // epilogue: fused combine (scale + scatter); C/D layout per m89/m91
#pragma unroll
  for (int m = 0; m < 4; ++m)
#pragma unroll
    for (int j = 0; j < 4; ++j) {
      const int slot = m0 + wm * 64 + m * 16 + gl * 4 + j;
      const int t = src[e * CAPACITY + slot];
      if (t >= 0) {
        const float p = prob[t];
        float* op = out + (size_t)t * N;
#pragma unroll
        for (int n = 0; n < 4; ++n) {
          const int col = n0 + wn * 64 + n * 16 + rl;
          op[col] = p * acc[m][n][j];
        }
      }
    }
}

extern "C" void kernel_launch(void* const* d_in, const int* in_sizes, int n_in,
                              void* d_out, int out_size, void* d_ws, size_t ws_size,
                              hipStream_t stream) {
  const float* x  = (const float*)d_in[0];
  const float* gw = (const float*)d_in[1];
  const float* w1 = (const float*)d_in[2];
  const float* w2 = (const float*)d_in[3];
  float* out = (float*)d_out;

  char* ws = (char*)d_ws;
  size_t off = 0;
  auto alloc = [&](size_t bytes) {
    void* p = ws + off;
    off += (bytes + 255) & ~(size_t)255;
    return p;
  };
  __bf16* W1bT = (__bf16*)alloc((size_t)NEXP * FDIM * DDIM * 2);   // [E][F][D] bf16
  __bf16* W2bT = (__bf16*)alloc((size_t)NEXP * DDIM * FDIM * 2);   // [E][D][F] bf16
  __bf16* Xb   = (__bf16*)alloc((size_t)NEXP * CAPACITY * DDIM * 2);
  __bf16* Hb   = (__bf16*)alloc((size_t)NEXP * CAPACITY * FDIM * 2);
  int*   eidx  = (int*)alloc(TOKENS * sizeof(int));
  float* prob  = (float*)alloc(TOKENS * sizeof(float));
  int*   srcm  = (int*)alloc(NEXP * CAPACITY * sizeof(int));
  int*   cnts  = (int*)alloc(NEXP * sizeof(int));
  (void)ws_size; (void)in_sizes; (void)n_in;

  hipMemsetAsync(d_out, 0, (size_t)out_size * sizeof(float), stream);  // dropped tokens -> 0

  gate_kernel<<<TOKENS, 64, 0, stream>>>(x, gw, eidx, prob);
  scan_kernel<<<1, 256, 0, stream>>>(eidx, srcm, cnts);
  // dispatch CONCURRENT WITH W1 transpose: grid = 10240 + 8192
  fused_dw1t_kernel<<<NWGD + NWGT1, 256, 0, stream>>>(x, srcm, Xb, w1, W1bT);
  // gemm1 (H = relu(Xb @ W1^T)) CONCURRENT WITH W2 transpose: grid = 2560 + 8192
  fused_g1w2t_kernel<<<NWG1 + NWGT2, 256, 0, stream>>>(
      Xb, W1bT, Hb, cnts, w2, W2bT);
  // out[t] = prob[t] * (H @ W2bT^T)[slot]: pure-bf16 form, grid = 8*10*8 = 640
  gemm2_kernel<<<(DDIM / 128) * NYT * NEXP, 256, 0, stream>>>(
      Hb, W2bT, out, srcm, prob, cnts,
      FDIM, (size_t)CAPACITY * FDIM, (size_t)DDIM * FDIM);
}